// Round 2
// baseline (414.421 us; speedup 1.0000x reference)
//
#include <hip/hip_runtime.h>

typedef __bf16 bf16x8 __attribute__((ext_vector_type(8)));
typedef float f32x4 __attribute__((ext_vector_type(4)));
typedef unsigned short us4 __attribute__((ext_vector_type(4)));

constexpr int TT = 2048;   // tokens
constexpr int CC = 2048;   // channels
constexpr int HH = 16;     // heads
constexpr int DD = 128;    // head dim

__device__ __forceinline__ unsigned short f2bf(float f) {
  unsigned u = __builtin_bit_cast(unsigned, f);
  u += 0x7FFFu + ((u >> 16) & 1u);
  return (unsigned short)(u >> 16);
}

// async global->LDS, 16B per lane. C-style casts lower to addrspacecast.
__device__ __forceinline__ void gld_lds16(const unsigned short* g, unsigned short* l) {
  __builtin_amdgcn_global_load_lds(
      (const __attribute__((address_space(1))) unsigned int*)g,
      (__attribute__((address_space(3))) unsigned int*)l,
      16, 0, 0);
}

// ---------------- f32 -> bf16 convert ----------------
__global__ __launch_bounds__(256) void k_f32_to_bf16(
    const float* __restrict__ src, unsigned short* __restrict__ dst, int n8) {
  int i = blockIdx.x * 256 + threadIdx.x;
  if (i >= n8) return;
  const float4* s = (const float4*)src;
  float4 a = s[2 * i], b = s[2 * i + 1];
  us4 lo = { f2bf(a.x), f2bf(a.y), f2bf(a.z), f2bf(a.w) };
  us4 hi = { f2bf(b.x), f2bf(b.y), f2bf(b.z), f2bf(b.w) };
  us4* d = (us4*)dst;
  d[2 * i] = lo;
  d[2 * i + 1] = hi;
}

// ---------------- GEMM: C = A(MxK) * B(NxK)^T, bf16 in, f32 out ----------------
// MODE 0: fused QKV epilogue (col<2048 -> Qf, <4096 -> new_k (h,t,d), else new_v)
// MODE 1: plain f32 store to out0[row*N + col]
template <int MODE>
__global__ __launch_bounds__(256) void k_gemm_bt(
    const unsigned short* __restrict__ A, const unsigned short* __restrict__ B,
    int M, int N, int K,
    float* __restrict__ out0, float* __restrict__ out1, float* __restrict__ out2) {
  __shared__ alignas(16) unsigned short As[128 * 64];
  __shared__ alignas(16) unsigned short Bs[128 * 64];
  const int tid = threadIdx.x;
  const int m0 = blockIdx.y * 128, n0 = blockIdx.x * 128;
  const int wid = tid >> 6, lane = tid & 63;
  const int wm = (wid >> 1) * 64, wn = (wid & 1) * 64;
  const int lr = lane & 15, lg = lane >> 4;
  f32x4 acc[4][4] = {};
  const int rowS = tid >> 3;        // 0..31 (+i*32)
  const int colS = (tid & 7) * 8;   // 0,8,..,56
  const unsigned short* ag = A + (size_t)(m0 + rowS) * K + colS;
  const unsigned short* bg = B + (size_t)(n0 + rowS) * K + colS;

  for (int k0 = 0; k0 < K; k0 += 64) {
#pragma unroll
    for (int i = 0; i < 4; ++i)
      gld_lds16(ag + (size_t)(i * 32) * K + k0, As + tid * 8 + i * 2048);
#pragma unroll
    for (int i = 0; i < 4; ++i)
      gld_lds16(bg + (size_t)(i * 32) * K + k0, Bs + tid * 8 + i * 2048);
    __syncthreads();
#pragma unroll
    for (int ks = 0; ks < 2; ++ks) {
      bf16x8 av[4], bv[4];
#pragma unroll
      for (int m = 0; m < 4; ++m)
        av[m] = *(const bf16x8*)(As + (wm + m * 16 + lr) * 64 + ks * 32 + lg * 8);
#pragma unroll
      for (int n = 0; n < 4; ++n)
        bv[n] = *(const bf16x8*)(Bs + (wn + n * 16 + lr) * 64 + ks * 32 + lg * 8);
#pragma unroll
      for (int m = 0; m < 4; ++m)
#pragma unroll
        for (int n = 0; n < 4; ++n)
          acc[m][n] = __builtin_amdgcn_mfma_f32_16x16x32_bf16(av[m], bv[n], acc[m][n], 0, 0, 0);
    }
    __syncthreads();
  }

#pragma unroll
  for (int m = 0; m < 4; ++m) {
    const int row = m0 + wm + m * 16 + lg * 4;
#pragma unroll
    for (int n = 0; n < 4; ++n) {
      const int col = n0 + wn + n * 16 + lr;
#pragma unroll
      for (int r = 0; r < 4; ++r) {
        float v = acc[m][n][r];
        int rr = row + r;
        if (MODE == 0) {
          if (col < 2048) {
            out0[(size_t)rr * 2048 + col] = v;
          } else if (col < 4096) {
            int c = col - 2048;
            out1[(size_t)(c >> 7) * (TT * DD) + (size_t)rr * DD + (c & 127)] = v;
          } else {
            int c = col - 4096;
            out2[(size_t)(c >> 7) * (TT * DD) + (size_t)rr * DD + (c & 127)] = v;
          }
        } else {
          out0[(size_t)rr * N + col] = v;
        }
      }
    }
  }
}

// ---------------- RoPE + scale, pack q/k as bf16 [h][t][d] ----------------
__global__ __launch_bounds__(256) void k_rope(
    const float* __restrict__ Qf, const float* __restrict__ Kraw,
    const float* __restrict__ sqk,
    unsigned short* __restrict__ qb, unsigned short* __restrict__ kb) {
  const int t = blockIdx.x;
  for (int i = threadIdx.x; i < HH * 64; i += 256) {
    int h = i >> 6, dp = i & 63;
    // theta = 10000^(-dp/64) = exp(-dp * ln(10000)/64)
    float theta = expf(-(float)dp * 0.14391156831212787f);
    float ang = (float)t * theta;
    float sn, cs;
    sincosf(ang, &sn, &cs);
    float qr = Qf[(size_t)t * CC + h * DD + dp];
    float qi = Qf[(size_t)t * CC + h * DD + dp + 64];
    const float* kp = Kraw + (size_t)h * TT * DD + (size_t)t * DD;
    float kr = kp[dp], ki = kp[dp + 64];
    float sr = sqk[h * DD + dp];
    float si = sqk[h * DD + dp + 64];
    // q gets sqk*sqrt(C) and the sqrt(D) score scale folded in: sqrt(2048)*sqrt(128)=512
    float qsr = sr * 512.0f, qsi = si * 512.0f;
    float ksr = sr * 45.25483399593904f, ksi = si * 45.25483399593904f; // sqrt(2048)
    unsigned short* qo = qb + ((size_t)h * TT + t) * DD;
    unsigned short* ko = kb + ((size_t)h * TT + t) * DD;
    qo[dp]      = f2bf((qr * cs - qi * sn) * qsr);
    qo[dp + 64] = f2bf((qr * sn + qi * cs) * qsi);
    ko[dp]      = f2bf((kr * cs - ki * sn) * ksr);
    ko[dp + 64] = f2bf((kr * sn + ki * cs) * ksi);
  }
}

// ---------------- V transpose: new_v f32 [h][t][d] -> vt bf16 [h][d][t] ----------------
__global__ __launch_bounds__(256) void k_vt(
    const float* __restrict__ Vraw, unsigned short* __restrict__ vt) {
  const int h = blockIdx.z;
  const int t0 = blockIdx.x * 64, d0 = blockIdx.y * 64;
  __shared__ unsigned short tile[64][65];
  const float* vp = Vraw + (size_t)h * TT * DD;
  for (int i = threadIdx.x; i < 4096; i += 256) {
    int r = i >> 6, c = i & 63;
    tile[r][c] = f2bf(vp[(size_t)(t0 + r) * DD + d0 + c]);
  }
  __syncthreads();
  unsigned short* op = vt + (size_t)h * DD * TT;
  for (int i = threadIdx.x; i < 4096; i += 256) {
    int dr = i >> 6, tc = i & 63;
    op[(size_t)(d0 + dr) * TT + t0 + tc] = tile[tc][dr];
  }
}

// ---------------- causal flash attention ----------------
// grid (32 qtiles, 16 heads), 256 threads = 4 independent waves (16 q-rows each)
__global__ __launch_bounds__(256) void k_attn(
    const unsigned short* __restrict__ qb, const unsigned short* __restrict__ kb,
    const unsigned short* __restrict__ vt, unsigned short* __restrict__ ob) {
  const int h = blockIdx.y;
  const int qt = blockIdx.x;
  const int wid = threadIdx.x >> 6, lane = threadIdx.x & 63;
  const int lr = lane & 15, lg = lane >> 4;
  __shared__ alignas(16) unsigned short P[4][16][40];
  const int q0 = qt * 64 + wid * 16;
  const unsigned short* qh = qb + (size_t)h * TT * DD;
  const unsigned short* kh = kb + (size_t)h * TT * DD;
  const unsigned short* vh = vt + (size_t)h * DD * TT;

  bf16x8 qf[4];
#pragma unroll
  for (int c = 0; c < 4; ++c)
    qf[c] = *(const bf16x8*)(qh + (size_t)(q0 + lr) * DD + c * 32 + lg * 8);

  f32x4 acc[8] = {};
  float mrow[4] = {-3e38f, -3e38f, -3e38f, -3e38f};
  float lsum[4] = {0.f, 0.f, 0.f, 0.f};

  for (int k0 = 0; k0 <= q0 + 15; k0 += 32) {
    f32x4 s0 = {}, s1 = {};
#pragma unroll
    for (int c = 0; c < 4; ++c) {
      bf16x8 kf0 = *(const bf16x8*)(kh + (size_t)(k0 + lr) * DD + c * 32 + lg * 8);
      bf16x8 kf1 = *(const bf16x8*)(kh + (size_t)(k0 + 16 + lr) * DD + c * 32 + lg * 8);
      s0 = __builtin_amdgcn_mfma_f32_16x16x32_bf16(qf[c], kf0, s0, 0, 0, 0);
      s1 = __builtin_amdgcn_mfma_f32_16x16x32_bf16(qf[c], kf1, s1, 0, 0, 0);
    }
    if (k0 + 31 > q0) {  // diagonal tiles need causal masking
#pragma unroll
      for (int r = 0; r < 4; ++r) {
        int rt = q0 + lg * 4 + r;
        if (k0 + lr > rt) s0[r] = -1e30f;
        if (k0 + 16 + lr > rt) s1[r] = -1e30f;
      }
    }
    float pmax[4];
#pragma unroll
    for (int r = 0; r < 4; ++r) pmax[r] = fmaxf(s0[r], s1[r]);
#pragma unroll
    for (int msk = 1; msk <= 8; msk <<= 1)
#pragma unroll
      for (int r = 0; r < 4; ++r) pmax[r] = fmaxf(pmax[r], __shfl_xor(pmax[r], msk));
    float p0[4], p1[4], ps[4], scl[4];
#pragma unroll
    for (int r = 0; r < 4; ++r) {
      float mn = fmaxf(mrow[r], pmax[r]);
      scl[r] = __expf(mrow[r] - mn);
      mrow[r] = mn;
      p0[r] = __expf(s0[r] - mn);
      p1[r] = __expf(s1[r] - mn);
      ps[r] = p0[r] + p1[r];
    }
#pragma unroll
    for (int msk = 1; msk <= 8; msk <<= 1)
#pragma unroll
      for (int r = 0; r < 4; ++r) ps[r] += __shfl_xor(ps[r], msk);
#pragma unroll
    for (int r = 0; r < 4; ++r) lsum[r] = lsum[r] * scl[r] + ps[r];
#pragma unroll
    for (int n = 0; n < 8; ++n)
#pragma unroll
      for (int r = 0; r < 4; ++r) acc[n][r] *= scl[r];
    // P -> LDS (per-wave region), then read back as MFMA A-fragment
#pragma unroll
    for (int r = 0; r < 4; ++r) {
      P[wid][lg * 4 + r][lr]      = f2bf(p0[r]);
      P[wid][lg * 4 + r][16 + lr] = f2bf(p1[r]);
    }
    asm volatile("s_waitcnt lgkmcnt(0)" ::: "memory");
    bf16x8 pf = *(const bf16x8*)(&P[wid][lr][lg * 8]);
#pragma unroll
    for (int n = 0; n < 8; ++n) {
      bf16x8 vf = *(const bf16x8*)(vh + (size_t)(n * 16 + lr) * TT + k0 + lg * 8);
      acc[n] = __builtin_amdgcn_mfma_f32_16x16x32_bf16(pf, vf, acc[n], 0, 0, 0);
    }
  }

  float inv[4];
#pragma unroll
  for (int r = 0; r < 4; ++r) inv[r] = 1.0f / lsum[r];
#pragma unroll
  for (int n = 0; n < 8; ++n)
#pragma unroll
    for (int r = 0; r < 4; ++r) {
      int t = q0 + lg * 4 + r;
      int c = h * DD + n * 16 + lr;
      ob[(size_t)t * CC + c] = f2bf(acc[n][r] * inv[r]);
    }
}

// ---------------- row l2norm ----------------
__global__ __launch_bounds__(256) void k_l2norm(
    const float* __restrict__ Of, float* __restrict__ out) {
  const int t = blockIdx.x;
  const int tid = threadIdx.x;
  const float4* p = (const float4*)(Of + (size_t)t * CC);
  float4 a = p[2 * tid], b = p[2 * tid + 1];
  float ss = a.x * a.x + a.y * a.y + a.z * a.z + a.w * a.w +
             b.x * b.x + b.y * b.y + b.z * b.z + b.w * b.w;
#pragma unroll
  for (int msk = 1; msk < 64; msk <<= 1) ss += __shfl_xor(ss, msk);
  __shared__ float red[4];
  if ((tid & 63) == 0) red[tid >> 6] = ss;
  __syncthreads();
  ss = red[0] + red[1] + red[2] + red[3];
  float sc = 1.0f / fmaxf(sqrtf(ss), 1e-12f);
  float4 oa = { a.x * sc, a.y * sc, a.z * sc, a.w * sc };
  float4 obv = { b.x * sc, b.y * sc, b.z * sc, b.w * sc };
  float4* o = (float4*)(out + (size_t)t * CC);
  o[2 * tid] = oa;
  o[2 * tid + 1] = obv;
}

extern "C" void kernel_launch(void* const* d_in, const int* in_sizes, int n_in,
                              void* d_out, int out_size, void* d_ws, size_t ws_size,
                              hipStream_t stream) {
  const float* x   = (const float*)d_in[0];
  const float* wq  = (const float*)d_in[1];
  const float* wk  = (const float*)d_in[2];
  const float* wv  = (const float*)d_in[3];
  const float* wo  = (const float*)d_in[4];
  const float* sqk = (const float*)d_in[5];

  float* out_norm = (float*)d_out;                                  // 4M f32
  float* out_k = out_norm + (size_t)4 * 1024 * 1024;                // new_k (h,t,d)
  float* out_v = out_norm + (size_t)8 * 1024 * 1024;                // new_v (h,t,d)

  char* ws = (char*)d_ws;
  unsigned short* xb  = (unsigned short*)(ws);                      // 8MB
  unsigned short* w1b = (unsigned short*)(ws + (8u << 20));         // 24MB (wq,wk,wv)
  unsigned short* wob = (unsigned short*)(ws + (32u << 20));        // 8MB
  unsigned short* qb  = (unsigned short*)(ws + (40u << 20));        // 8MB
  unsigned short* kb  = (unsigned short*)(ws + (48u << 20));        // 8MB
  unsigned short* vtb = (unsigned short*)(ws + (56u << 20));        // 8MB
  unsigned short* obb = (unsigned short*)(ws + (64u << 20));        // 8MB
  float* Qf = (float*)(ws + (72u << 20));                           // 16MB (Q f32, reused as Of)

  const int n8 = (CC * CC) / 8;  // 524288 vec8 per matrix
  k_f32_to_bf16<<<n8 / 256, 256, 0, stream>>>(x,  xb, n8);
  k_f32_to_bf16<<<n8 / 256, 256, 0, stream>>>(wq, w1b, n8);
  k_f32_to_bf16<<<n8 / 256, 256, 0, stream>>>(wk, w1b + (size_t)4 * 1024 * 1024, n8);
  k_f32_to_bf16<<<n8 / 256, 256, 0, stream>>>(wv, w1b + (size_t)8 * 1024 * 1024, n8);
  k_f32_to_bf16<<<n8 / 256, 256, 0, stream>>>(wo, wob, n8);

  // fused QKV projection: C = x @ [wq;wk;wv]^T  (2048 x 6144)
  k_gemm_bt<0><<<dim3(48, 16), 256, 0, stream>>>(xb, w1b, TT, 3 * CC, CC, Qf, out_k, out_v);

  k_rope<<<TT, 256, 0, stream>>>(Qf, out_k, sqk, qb, kb);
  k_vt<<<dim3(32, 2, 16), 256, 0, stream>>>(out_v, vtb);

  k_attn<<<dim3(32, 16), 256, 0, stream>>>(qb, kb, vtb, obb);

  // output projection: Of = attn_out @ wo^T
  k_gemm_bt<1><<<dim3(16, 16), 256, 0, stream>>>(obb, wob, TT, CC, CC, Qf, nullptr, nullptr);

  k_l2norm<<<TT, 256, 0, stream>>>(Qf, out_norm);
}